// Round 26
// baseline (192.769 us; speedup 1.0000x reference)
//
#include <hip/hip_runtime.h>

#define CC 128      // all channel dims are 128
#define TILE 1024   // scan tile
#define NB1 1024    // agg1/stats blocks

typedef unsigned int uint;
typedef unsigned short ushort;
typedef __attribute__((ext_vector_type(8))) short short8;
typedef __attribute__((ext_vector_type(4))) short short4v;
typedef __attribute__((ext_vector_type(4))) float f32x4;

__device__ __forceinline__ ushort f2bf(float f) {
    uint u = __float_as_uint(f);
    u += 0x7FFFu + ((u >> 16) & 1u);   // round-to-nearest-even
    return (ushort)(u >> 16);
}
__device__ __forceinline__ float bf2f(ushort h) {
    return __uint_as_float(((uint)h) << 16);
}

// ---------------- prep: zero deg + convert both W -> Wt bf16 (one launch) ----
__global__ __launch_bounds__(256) void prep(int4* __restrict__ deg4, int n4, int nzb,
                                            const float* __restrict__ W1, ushort* __restrict__ Wt1,
                                            const float* __restrict__ W2, ushort* __restrict__ Wt2) {
    int b = blockIdx.x;
    if (b < nzb) {
        int i = b * 256 + threadIdx.x;
        if (i < n4) deg4[i] = int4{0, 0, 0, 0};
    } else if (b < nzb + 64) {
        int t = (b - nzb) * 256 + threadIdx.x;
        int k = t >> 7, c = t & 127;
        Wt1[c * CC + k] = f2bf(W1[k * CC + c]);
    } else {
        int t = (b - nzb - 64) * 256 + threadIdx.x;
        int k = t >> 7, c = t & 127;
        Wt2[c * CC + k] = f2bf(W2[k * CC + c]);
    }
}

// ---------------- degree count ----------------
__global__ __launch_bounds__(256) void count_deg(const int* __restrict__ dst,
                                                 int* __restrict__ deg, int e) {
    int i = blockIdx.x * 256 + threadIdx.x;
    if (i < e) atomicAdd(&deg[dst[i]], 1);
}

// ---------------- scan stage 1: per-tile sums ----------------
__global__ __launch_bounds__(256) void scan_tile_sums(const int* __restrict__ deg,
                                                      int* __restrict__ tsum, int n) {
    __shared__ int red[256];
    int base = blockIdx.x * TILE;
    int s = 0;
    for (int i = threadIdx.x; i < TILE; i += 256) {
        int g = base + i;
        s += (g < n) ? deg[g] : 0;
    }
    red[threadIdx.x] = s;
    __syncthreads();
    for (int off = 128; off > 0; off >>= 1) {
        if (threadIdx.x < off) red[threadIdx.x] += red[threadIdx.x + off];
        __syncthreads();
    }
    if (threadIdx.x == 0) tsum[blockIdx.x] = red[0];
}

// scan stage 2 (scan_tops merged): each block derives its tile prefix from raw
// tsum, then in-tile exclusive scan; also produces dinv.
__global__ __launch_bounds__(256) void scan_final(const int* __restrict__ deg,
                                                  const int* __restrict__ tsum, int nt,
                                                  int* __restrict__ rowptr,
                                                  int* __restrict__ cursor,
                                                  float* __restrict__ dinv, int n) {
    __shared__ int pre[256];
    __shared__ int lds[256];
    int t = threadIdx.x;
    pre[t] = (t < nt && t < (int)blockIdx.x) ? tsum[t] : 0;
    __syncthreads();
    for (int off = 128; off > 0; off >>= 1) {
        if (t < off) pre[t] += pre[t + off];
        __syncthreads();
    }
    int tile_base = pre[0];
    __syncthreads();

    int base = blockIdx.x * TILE;
    int g0 = base + t * 4;
    int v[4];
#pragma unroll
    for (int k = 0; k < 4; ++k) {
        int g = g0 + k;
        v[k] = (g < n) ? deg[g] : 0;
    }
    int tl = v[0] + v[1] + v[2] + v[3];
    lds[t] = tl;
    __syncthreads();
    for (int off = 1; off < 256; off <<= 1) {
        int add = (t >= off) ? lds[t - off] : 0;
        __syncthreads();
        lds[t] += add;
        __syncthreads();
    }
    int excl = lds[t] - tl + tile_base;
#pragma unroll
    for (int k = 0; k < 4; ++k) {
        int g = g0 + k;
        if (g < n) {
            rowptr[g] = excl;
            cursor[g] = excl;
            dinv[g] = rsqrtf((float)v[k] + 1.0f);
            if (g == n - 1) rowptr[n] = excl + v[k];
            excl += v[k];
        }
    }
}

// ---------------- MFMA GEMM (one-shot 64-row blocks), fused fill_csr --------
// Y[r][c] = bf16( sum_k IN[r][k]*W[k][c] );  IN = X or relu(bn(X)).
// B staged via global_load_lds(16B): linear LDS dest + pre-swizzled source.
// Swapped-operand mfma(b,a) -> lane owns its row -> packed 8B stores.
// FILL: blocks >= gemm_blocks instead run fill_csr (hides the 39us fill).
template <typename TIN, bool BN, bool FILL>
__global__ __launch_bounds__(256) void gemm_mfma(const TIN* __restrict__ X,
                                                 const ushort* __restrict__ Wt,
                                                 ushort* __restrict__ Y, int n,
                                                 const float* __restrict__ coef,
                                                 const int* __restrict__ src,
                                                 const int* __restrict__ dst,
                                                 int* __restrict__ cursor,
                                                 int* __restrict__ csr, int e,
                                                 int gemm_blocks) {
    if constexpr (FILL) {
        if (blockIdx.x >= gemm_blocks) {
            int i = (blockIdx.x - gemm_blocks) * 256 + threadIdx.x;
            if (i < e) {
                int slot = atomicAdd(&cursor[dst[i]], 1);
                csr[slot] = src[i];
            }
            return;
        }
    }
    __shared__ ushort sB[CC * CC];   // 32 KB: sB[col][k] bf16, swizzled content
    char* sBc = (char*)sB;
    const int t = threadIdx.x;
    const int wid = t >> 6;
    const int lane = t & 63;
    const int l15 = lane & 15;
    const int lhi = lane >> 4;                 // 0..3
    const int row0 = blockIdx.x * 64;
    const int gr = row0 + wid * 16 + l15;      // this lane's row
    const bool rv = gr < n;
    const TIN* xrow = X + (size_t)gr * CC;

    auto loadA = [&](int kc) -> short8 {
        short8 r = short8{0, 0, 0, 0, 0, 0, 0, 0};
        if (rv) {
            const int koff = kc * 32 + lhi * 8;
            float sc[8], be[8];
            if constexpr (BN) {
                float4 s0 = *(const float4*)(coef + koff);
                float4 s1 = *(const float4*)(coef + koff + 4);
                float4 e0 = *(const float4*)(coef + CC + koff);
                float4 e1 = *(const float4*)(coef + CC + koff + 4);
                sc[0]=s0.x; sc[1]=s0.y; sc[2]=s0.z; sc[3]=s0.w;
                sc[4]=s1.x; sc[5]=s1.y; sc[6]=s1.z; sc[7]=s1.w;
                be[0]=e0.x; be[1]=e0.y; be[2]=e0.z; be[3]=e0.w;
                be[4]=e1.x; be[5]=e1.y; be[6]=e1.z; be[7]=e1.w;
            }
            if constexpr (sizeof(TIN) == 4) {   // fp32 input
                const float4* xp = (const float4*)(xrow + koff);
                float4 lo = xp[0], hi = xp[1];
                float f[8] = {lo.x, lo.y, lo.z, lo.w, hi.x, hi.y, hi.z, hi.w};
#pragma unroll
                for (int i = 0; i < 8; ++i) {
                    if constexpr (BN) f[i] = fmaxf(0.f, fmaf(f[i], sc[i], be[i]));
                    r[i] = (short)f2bf(f[i]);
                }
            } else {                            // bf16 input
                short8 v = *(const short8*)((const ushort*)xrow + koff);
                if constexpr (BN) {
#pragma unroll
                    for (int i = 0; i < 8; ++i) {
                        float f = bf2f((ushort)v[i]);
                        f = fmaxf(0.f, fmaf(f, sc[i], be[i]));
                        v[i] = (short)f2bf(f);
                    }
                }
                r = v;
            }
        }
        return r;
    };

    // ---- issue all 4 A-fragments up-front (overlaps B staging below) ----
    short8 a[4];
#pragma unroll
    for (int kc = 0; kc < 4; ++kc) a[kc] = loadA(kc);

    // ---- stage B via global_load_lds: linear LDS dest, pre-swizzled source --
    {
        const char* WtB = (const char*)Wt;
#pragma unroll
        for (int it = 0; it < 8; ++it) {
            int D = (it * 256 + t) * 16;                   // linear dest byte
            int S = D ^ (((D >> 8) & 7) << 4);             // swizzle involution
            __builtin_amdgcn_global_load_lds(
                (const __attribute__((address_space(1))) void*)(WtB + S),
                (__attribute__((address_space(3))) void*)(sBc + (it * 4096 + wid * 1024)),
                16, 0, 0);
        }
    }
    __syncthreads();

    f32x4 acc[8];
#pragma unroll
    for (int j = 0; j < 8; ++j) acc[j] = f32x4{0.f, 0.f, 0.f, 0.f};

#pragma unroll
    for (int kc = 0; kc < 4; ++kc) {
        const int koff = kc * 32 + lhi * 8;
        short8 b[8];
#pragma unroll
        for (int tn = 0; tn < 8; ++tn) {
            int col = tn * 16 + l15;
            int byte = (col * CC + koff) * 2;
            byte ^= (col & 7) << 4;
            b[tn] = *(const short8*)(sBc + byte);
        }
        // swapped operands: D = B_frag x A_frag = C^T layout
#pragma unroll
        for (int tn = 0; tn < 8; ++tn)
            acc[tn] = __builtin_amdgcn_mfma_f32_16x16x32_bf16(b[tn], a[kc], acc[tn], 0, 0, 0);
    }

    // ---- epilogue: lane owns row gr; acc[tn][i] = C[gr][tn*16 + lhi*4 + i] ----
    if (rv) {
        ushort* yrow = Y + (size_t)gr * CC;
#pragma unroll
        for (int tn = 0; tn < 8; ++tn) {
            short4v v;
#pragma unroll
            for (int i = 0; i < 4; ++i) v[i] = (short)f2bf(acc[tn][i]);
            *(short4v*)(yrow + tn * 16 + lhi * 4) = v;
        }
    }
}

// ---------------- CSR aggregation (grid-stride), optional fused BN stats -----
// OUT[d] = dinv[d] * (dinv[d]*H[d] + sum_{s in N(d)} H[s]*dinv[s]) + bias.
template <bool OUT_BF16, bool STATS>
__global__ __launch_bounds__(256) void aggregate_csr(const ushort* __restrict__ HS,
                                                     const int* __restrict__ rowptr,
                                                     const int* __restrict__ csr,
                                                     const float* __restrict__ dinv,
                                                     const float* __restrict__ bias,
                                                     void* __restrict__ OUT,
                                                     float* __restrict__ partT, int n) {
    int slot = threadIdx.x >> 4;
    int j = threadIdx.x & 15;
    const ushort* colbase = HS + (size_t)j * 8;

    float4 b0 = ((const float4*)bias)[j * 2];
    float4 b1 = ((const float4*)bias)[j * 2 + 1];
    float bb[8] = {b0.x, b0.y, b0.z, b0.w, b1.x, b1.y, b1.z, b1.w};

    float s[8], q[8];
    if constexpr (STATS) {
#pragma unroll
        for (int i = 0; i < 8; ++i) { s[i] = 0.f; q[i] = 0.f; }
    }

    int stride = gridDim.x * 16;
    for (int d = blockIdx.x * 16 + slot; d < n; d += stride) {
        float dd = dinv[d];
        float acc[8];
        {
            short8 v = *(const short8*)(colbase + (size_t)d * CC);
#pragma unroll
            for (int i = 0; i < 8; ++i) acc[i] = bf2f((ushort)v[i]) * dd;
        }

        int k = rowptr[d], end = rowptr[d + 1];
        while (k + 4 <= end) {
            int s0 = csr[k], s1 = csr[k + 1], s2 = csr[k + 2], s3 = csr[k + 3];
            float w0 = dinv[s0], w1 = dinv[s1], w2 = dinv[s2], w3 = dinv[s3];
            short8 v0 = *(const short8*)(colbase + (size_t)s0 * CC);
            short8 v1 = *(const short8*)(colbase + (size_t)s1 * CC);
            short8 v2 = *(const short8*)(colbase + (size_t)s2 * CC);
            short8 v3 = *(const short8*)(colbase + (size_t)s3 * CC);
#pragma unroll
            for (int i = 0; i < 8; ++i)
                acc[i] += (fmaf(bf2f((ushort)v0[i]), w0, bf2f((ushort)v1[i]) * w1)) +
                          (fmaf(bf2f((ushort)v2[i]), w2, bf2f((ushort)v3[i]) * w3));
            k += 4;
        }
        if (k + 2 <= end) {
            int s0 = csr[k], s1 = csr[k + 1];
            float w0 = dinv[s0], w1 = dinv[s1];
            short8 v0 = *(const short8*)(colbase + (size_t)s0 * CC);
            short8 v1 = *(const short8*)(colbase + (size_t)s1 * CC);
#pragma unroll
            for (int i = 0; i < 8; ++i)
                acc[i] += fmaf(bf2f((ushort)v0[i]), w0, bf2f((ushort)v1[i]) * w1);
            k += 2;
        }
        if (k < end) {
            int s0 = csr[k];
            float w0 = dinv[s0];
            short8 v0 = *(const short8*)(colbase + (size_t)s0 * CC);
#pragma unroll
            for (int i = 0; i < 8; ++i) acc[i] = fmaf(bf2f((ushort)v0[i]), w0, acc[i]);
        }

        float o[8];
#pragma unroll
        for (int i = 0; i < 8; ++i) o[i] = fmaf(acc[i], dd, bb[i]);

        if constexpr (STATS) {
#pragma unroll
            for (int i = 0; i < 8; ++i) { s[i] += o[i]; q[i] = fmaf(o[i], o[i], q[i]); }
        }

        if constexpr (OUT_BF16) {
            short8 v;
#pragma unroll
            for (int i = 0; i < 8; ++i) v[i] = (short)f2bf(o[i]);
            *(short8*)((ushort*)OUT + (size_t)d * CC + j * 8) = v;
        } else {
            float* op = (float*)OUT + (size_t)d * CC + j * 8;
#pragma unroll
            for (int i = 0; i < 8; ++i) op[i] = o[i];
        }
    }

    if constexpr (STATS) {
        __shared__ float reds[16 * 16 * 9];
        __shared__ float redq[16 * 16 * 9];
        float* ps = reds + (slot * 16 + j) * 9;
        float* pq = redq + (slot * 16 + j) * 9;
#pragma unroll
        for (int i = 0; i < 8; ++i) { ps[i] = s[i]; pq[i] = q[i]; }
        __syncthreads();
        for (int off = 8; off > 0; off >>= 1) {
            if (slot < off) {
                float* os = reds + ((slot + off) * 16 + j) * 9;
                float* oq = redq + ((slot + off) * 16 + j) * 9;
#pragma unroll
                for (int i = 0; i < 8; ++i) { ps[i] += os[i]; pq[i] += oq[i]; }
            }
            __syncthreads();
        }
        if (slot == 0) {
#pragma unroll
            for (int i = 0; i < 8; ++i) {
                partT[(size_t)(j * 8 + i) * NB1 + blockIdx.x] = ps[i];
                partT[(size_t)(CC + j * 8 + i) * NB1 + blockIdx.x] = pq[i];
            }
        }
    }
}

// ---------------- BN finish: reduce partials + compute coef (one launch) -----
__global__ __launch_bounds__(256) void bn_finish(const float* __restrict__ partT,
                                                 const float* __restrict__ gamma,
                                                 const float* __restrict__ beta,
                                                 float* __restrict__ coef, int n) {
    __shared__ float red[256];
    int c = blockIdx.x;
    int t = threadIdx.x;

    f32x4 v = ((const f32x4*)(partT + (size_t)c * NB1))[t];
    red[t] = v.x + v.y + v.z + v.w;
    __syncthreads();
    for (int off = 128; off > 0; off >>= 1) {
        if (t < off) red[t] += red[t + off];
        __syncthreads();
    }
    float S = red[0];
    __syncthreads();

    v = ((const f32x4*)(partT + (size_t)(CC + c) * NB1))[t];
    red[t] = v.x + v.y + v.z + v.w;
    __syncthreads();
    for (int off = 128; off > 0; off >>= 1) {
        if (t < off) red[t] += red[t + off];
        __syncthreads();
    }
    float Q = red[0];

    if (t == 0) {
        float inv_n = 1.0f / (float)n;
        float mean = S * inv_n;
        float var = Q * inv_n - mean * mean;
        float sc = gamma[c] * rsqrtf(var + 1e-5f);
        coef[c] = sc;
        coef[CC + c] = beta[c] - mean * sc;
    }
}

extern "C" void kernel_launch(void* const* d_in, const int* in_sizes, int n_in,
                              void* d_out, int out_size, void* d_ws, size_t ws_size,
                              hipStream_t stream) {
    const float* x      = (const float*)d_in[0];
    const float* W1     = (const float*)d_in[1];
    const float* b1     = (const float*)d_in[2];
    const float* gamma1 = (const float*)d_in[3];
    const float* beta1  = (const float*)d_in[4];
    const float* W2     = (const float*)d_in[5];
    const float* b2     = (const float*)d_in[6];
    const int*   edge   = (const int*)d_in[7];

    int n = in_sizes[0] / CC;
    int e = in_sizes[7] / 2;
    const int* src = edge;
    const int* dst = edge + e;

    float* out = (float*)d_out;
    char* ws = (char*)d_ws;
    ushort* hs   = (ushort*)ws;  ws += (size_t)n * CC * 2;   // gemm out (bf16)
    ushort* A    = (ushort*)ws;  ws += (size_t)n * CC * 2;   // agg1 out (bf16)
    ushort* Wt1  = (ushort*)ws;  ws += CC * CC * 2;
    ushort* Wt2  = (ushort*)ws;  ws += CC * CC * 2;
    int*   deg    = (int*)ws;    ws += (size_t)((n + 3) & ~3) * 4;
    float* dinv   = (float*)ws;  ws += (size_t)n * 4;
    int*   rowptr = (int*)ws;    ws += (size_t)(n + 1) * 4;
    int*   cursor = (int*)ws;    ws += (size_t)n * 4;
    int*   csr    = (int*)ws;    ws += (size_t)e * 4;
    int*   tsum   = (int*)ws;    ws += 4096;
    float* coef   = (float*)ws;  ws += 2 * CC * 4;
    float* partT  = (float*)ws;  ws += (size_t)2 * CC * NB1 * 4;   // 1 MB

    int ntiles = (n + TILE - 1) / TILE;
    int gemm_grid = (n + 63) / 64;
    int agg_grid = (n + 15) / 16;
    int n4 = (n + 3) / 4;
    int nzb = (n4 + 255) / 256;
    int edge_blocks = (e + 255) / 256;

    // ---- prep: zero deg + convert W1,W2 ----
    prep<<<nzb + 128, 256, 0, stream>>>((int4*)deg, n4, nzb, W1, Wt1, W2, Wt2);

    // ---- degree count (exposed; cheaper than fill) ----
    count_deg<<<edge_blocks, 256, 0, stream>>>(dst, deg, e);

    // ---- scans (+dinv) ----
    scan_tile_sums<<<ntiles, 256, 0, stream>>>(deg, tsum, n);
    scan_final<<<ntiles, 256, 0, stream>>>(deg, tsum, ntiles, rowptr, cursor, dinv, n);

    // ---- mega: layer-1 GEMM || fill_csr (hides the expensive fill) ----
    gemm_mfma<float, false, true><<<gemm_grid + edge_blocks, 256, 0, stream>>>(
        x, Wt1, hs, n, nullptr, src, dst, cursor, csr, e, gemm_grid);

    // ---- layer 1 aggregation + fused BN stats (grid-stride, NB1 blocks) ----
    aggregate_csr<true, true><<<NB1, 256, 0, stream>>>(hs, rowptr, csr, dinv, b1,
                                                       A, partT, n);

    // ---- BN finish: reduce partials + coefficients ----
    bn_finish<<<CC, 256, 0, stream>>>(partT, gamma1, beta1, coef, n);

    // ---- layer 2 (BN+ReLU fused into A-fragment load) ----
    gemm_mfma<ushort, true, false><<<gemm_grid, 256, 0, stream>>>(
        A, Wt2, hs, n, coef, nullptr, nullptr, nullptr, nullptr, 0, gemm_grid);
    aggregate_csr<false, false><<<agg_grid, 256, 0, stream>>>(hs, rowptr, csr, dinv, b2,
                                                              out, nullptr, n);
}

// Round 27
// 162.606 us; speedup vs baseline: 1.1855x; 1.1855x over previous
//
#include <hip/hip_runtime.h>

#define CC 128      // all channel dims are 128
#define TILE 1024   // scan tile
#define NB1 1024    // agg1/stats blocks

typedef unsigned int uint;
typedef unsigned short ushort;
typedef __attribute__((ext_vector_type(8))) short short8;
typedef __attribute__((ext_vector_type(4))) short short4v;
typedef __attribute__((ext_vector_type(4))) float f32x4;

__device__ __forceinline__ ushort f2bf(float f) {
    uint u = __float_as_uint(f);
    u += 0x7FFFu + ((u >> 16) & 1u);   // round-to-nearest-even
    return (ushort)(u >> 16);
}
__device__ __forceinline__ float bf2f(ushort h) {
    return __uint_as_float(((uint)h) << 16);
}

// ---------------- prep: zero deg + convert both W -> Wt bf16 (one launch) ----
__global__ __launch_bounds__(256) void prep(int4* __restrict__ deg4, int n4, int nzb,
                                            const float* __restrict__ W1, ushort* __restrict__ Wt1,
                                            const float* __restrict__ W2, ushort* __restrict__ Wt2) {
    int b = blockIdx.x;
    if (b < nzb) {
        int i = b * 256 + threadIdx.x;
        if (i < n4) deg4[i] = int4{0, 0, 0, 0};
    } else if (b < nzb + 64) {
        int t = (b - nzb) * 256 + threadIdx.x;
        int k = t >> 7, c = t & 127;
        Wt1[c * CC + k] = f2bf(W1[k * CC + c]);
    } else {
        int t = (b - nzb - 64) * 256 + threadIdx.x;
        int k = t >> 7, c = t & 127;
        Wt2[c * CC + k] = f2bf(W2[k * CC + c]);
    }
}

// ---------------- scan stage 1: per-tile sums ----------------
__global__ __launch_bounds__(256) void scan_tile_sums(const int* __restrict__ deg,
                                                      int* __restrict__ tsum, int n) {
    __shared__ int red[256];
    int base = blockIdx.x * TILE;
    int s = 0;
    for (int i = threadIdx.x; i < TILE; i += 256) {
        int g = base + i;
        s += (g < n) ? deg[g] : 0;
    }
    red[threadIdx.x] = s;
    __syncthreads();
    for (int off = 128; off > 0; off >>= 1) {
        if (threadIdx.x < off) red[threadIdx.x] += red[threadIdx.x + off];
        __syncthreads();
    }
    if (threadIdx.x == 0) tsum[blockIdx.x] = red[0];
}

// scan stage 2 (scan_tops merged): each block derives its tile prefix from raw
// tsum, then in-tile exclusive scan; also produces dinv. (no cursor needed)
__global__ __launch_bounds__(256) void scan_final(const int* __restrict__ deg,
                                                  const int* __restrict__ tsum, int nt,
                                                  int* __restrict__ rowptr,
                                                  float* __restrict__ dinv, int n) {
    __shared__ int pre[256];
    __shared__ int lds[256];
    int t = threadIdx.x;
    pre[t] = (t < nt && t < (int)blockIdx.x) ? tsum[t] : 0;
    __syncthreads();
    for (int off = 128; off > 0; off >>= 1) {
        if (t < off) pre[t] += pre[t + off];
        __syncthreads();
    }
    int tile_base = pre[0];
    __syncthreads();

    int base = blockIdx.x * TILE;
    int g0 = base + t * 4;
    int v[4];
#pragma unroll
    for (int k = 0; k < 4; ++k) {
        int g = g0 + k;
        v[k] = (g < n) ? deg[g] : 0;
    }
    int tl = v[0] + v[1] + v[2] + v[3];
    lds[t] = tl;
    __syncthreads();
    for (int off = 1; off < 256; off <<= 1) {
        int add = (t >= off) ? lds[t - off] : 0;
        __syncthreads();
        lds[t] += add;
        __syncthreads();
    }
    int excl = lds[t] - tl + tile_base;
#pragma unroll
    for (int k = 0; k < 4; ++k) {
        int g = g0 + k;
        if (g < n) {
            rowptr[g] = excl;
            dinv[g] = rsqrtf((float)v[k] + 1.0f);
            if (g == n - 1) rowptr[n] = excl + v[k];
            excl += v[k];
        }
    }
}

// ---------------- CSR fill: ATOMIC-FREE via precomputed rank ----------------
// slot = rowptr[dst[i]] + rank[i]  (rank captured during count_deg)
__global__ __launch_bounds__(256) void fill_csr(const int* __restrict__ src,
                                                const int* __restrict__ dst,
                                                const int* __restrict__ rowptr,
                                                const int* __restrict__ rank,
                                                int* __restrict__ csr, int e) {
    int i = blockIdx.x * 256 + threadIdx.x;
    if (i < e) {
        csr[rowptr[dst[i]] + rank[i]] = src[i];
    }
}

// ---------------- MFMA GEMM (one-shot 64-row blocks), fused count_deg -------
// Y[r][c] = bf16( sum_k IN[r][k]*W[k][c] );  IN = X or relu(bn(X)).
// B staged via global_load_lds(16B): linear LDS dest + pre-swizzled source.
// Swapped-operand mfma(b,a) -> lane owns its row -> packed 8B stores.
// COUNT: blocks >= gemm_blocks run count_deg AND capture each edge's rank
// (the atomicAdd return value) for the later atomic-free fill_csr.
template <typename TIN, bool BN, bool COUNT>
__global__ __launch_bounds__(256) void gemm_mfma(const TIN* __restrict__ X,
                                                 const ushort* __restrict__ Wt,
                                                 ushort* __restrict__ Y, int n,
                                                 const float* __restrict__ coef,
                                                 const int* __restrict__ dst,
                                                 int* __restrict__ deg,
                                                 int* __restrict__ rank, int e,
                                                 int gemm_blocks) {
    if constexpr (COUNT) {
        if (blockIdx.x >= gemm_blocks) {
            int i = (blockIdx.x - gemm_blocks) * 256 + threadIdx.x;
            if (i < e) rank[i] = atomicAdd(&deg[dst[i]], 1);
            return;
        }
    }
    __shared__ ushort sB[CC * CC];   // 32 KB: sB[col][k] bf16, swizzled content
    char* sBc = (char*)sB;
    const int t = threadIdx.x;
    const int wid = t >> 6;
    const int lane = t & 63;
    const int l15 = lane & 15;
    const int lhi = lane >> 4;                 // 0..3
    const int row0 = blockIdx.x * 64;
    const int gr = row0 + wid * 16 + l15;      // this lane's row
    const bool rv = gr < n;
    const TIN* xrow = X + (size_t)gr * CC;

    auto loadA = [&](int kc) -> short8 {
        short8 r = short8{0, 0, 0, 0, 0, 0, 0, 0};
        if (rv) {
            const int koff = kc * 32 + lhi * 8;
            float sc[8], be[8];
            if constexpr (BN) {
                float4 s0 = *(const float4*)(coef + koff);
                float4 s1 = *(const float4*)(coef + koff + 4);
                float4 e0 = *(const float4*)(coef + CC + koff);
                float4 e1 = *(const float4*)(coef + CC + koff + 4);
                sc[0]=s0.x; sc[1]=s0.y; sc[2]=s0.z; sc[3]=s0.w;
                sc[4]=s1.x; sc[5]=s1.y; sc[6]=s1.z; sc[7]=s1.w;
                be[0]=e0.x; be[1]=e0.y; be[2]=e0.z; be[3]=e0.w;
                be[4]=e1.x; be[5]=e1.y; be[6]=e1.z; be[7]=e1.w;
            }
            if constexpr (sizeof(TIN) == 4) {   // fp32 input
                const float4* xp = (const float4*)(xrow + koff);
                float4 lo = xp[0], hi = xp[1];
                float f[8] = {lo.x, lo.y, lo.z, lo.w, hi.x, hi.y, hi.z, hi.w};
#pragma unroll
                for (int i = 0; i < 8; ++i) {
                    if constexpr (BN) f[i] = fmaxf(0.f, fmaf(f[i], sc[i], be[i]));
                    r[i] = (short)f2bf(f[i]);
                }
            } else {                            // bf16 input
                short8 v = *(const short8*)((const ushort*)xrow + koff);
                if constexpr (BN) {
#pragma unroll
                    for (int i = 0; i < 8; ++i) {
                        float f = bf2f((ushort)v[i]);
                        f = fmaxf(0.f, fmaf(f, sc[i], be[i]));
                        v[i] = (short)f2bf(f);
                    }
                }
                r = v;
            }
        }
        return r;
    };

    // ---- issue all 4 A-fragments up-front (overlaps B staging below) ----
    short8 a[4];
#pragma unroll
    for (int kc = 0; kc < 4; ++kc) a[kc] = loadA(kc);

    // ---- stage B via global_load_lds: linear LDS dest, pre-swizzled source --
    {
        const char* WtB = (const char*)Wt;
#pragma unroll
        for (int it = 0; it < 8; ++it) {
            int D = (it * 256 + t) * 16;                   // linear dest byte
            int S = D ^ (((D >> 8) & 7) << 4);             // swizzle involution
            __builtin_amdgcn_global_load_lds(
                (const __attribute__((address_space(1))) void*)(WtB + S),
                (__attribute__((address_space(3))) void*)(sBc + (it * 4096 + wid * 1024)),
                16, 0, 0);
        }
    }
    __syncthreads();

    f32x4 acc[8];
#pragma unroll
    for (int j = 0; j < 8; ++j) acc[j] = f32x4{0.f, 0.f, 0.f, 0.f};

#pragma unroll
    for (int kc = 0; kc < 4; ++kc) {
        const int koff = kc * 32 + lhi * 8;
        short8 b[8];
#pragma unroll
        for (int tn = 0; tn < 8; ++tn) {
            int col = tn * 16 + l15;
            int byte = (col * CC + koff) * 2;
            byte ^= (col & 7) << 4;
            b[tn] = *(const short8*)(sBc + byte);
        }
        // swapped operands: D = B_frag x A_frag = C^T layout
#pragma unroll
        for (int tn = 0; tn < 8; ++tn)
            acc[tn] = __builtin_amdgcn_mfma_f32_16x16x32_bf16(b[tn], a[kc], acc[tn], 0, 0, 0);
    }

    // ---- epilogue: lane owns row gr; acc[tn][i] = C[gr][tn*16 + lhi*4 + i] ----
    if (rv) {
        ushort* yrow = Y + (size_t)gr * CC;
#pragma unroll
        for (int tn = 0; tn < 8; ++tn) {
            short4v v;
#pragma unroll
            for (int i = 0; i < 4; ++i) v[i] = (short)f2bf(acc[tn][i]);
            *(short4v*)(yrow + tn * 16 + lhi * 4) = v;
        }
    }
}

// ---------------- CSR aggregation (grid-stride), optional fused BN stats -----
// OUT[d] = dinv[d] * (dinv[d]*H[d] + sum_{s in N(d)} H[s]*dinv[s]) + bias.
template <bool OUT_BF16, bool STATS>
__global__ __launch_bounds__(256) void aggregate_csr(const ushort* __restrict__ HS,
                                                     const int* __restrict__ rowptr,
                                                     const int* __restrict__ csr,
                                                     const float* __restrict__ dinv,
                                                     const float* __restrict__ bias,
                                                     void* __restrict__ OUT,
                                                     float* __restrict__ partT, int n) {
    int slot = threadIdx.x >> 4;
    int j = threadIdx.x & 15;
    const ushort* colbase = HS + (size_t)j * 8;

    float4 b0 = ((const float4*)bias)[j * 2];
    float4 b1 = ((const float4*)bias)[j * 2 + 1];
    float bb[8] = {b0.x, b0.y, b0.z, b0.w, b1.x, b1.y, b1.z, b1.w};

    float s[8], q[8];
    if constexpr (STATS) {
#pragma unroll
        for (int i = 0; i < 8; ++i) { s[i] = 0.f; q[i] = 0.f; }
    }

    int stride = gridDim.x * 16;
    for (int d = blockIdx.x * 16 + slot; d < n; d += stride) {
        float dd = dinv[d];
        float acc[8];
        {
            short8 v = *(const short8*)(colbase + (size_t)d * CC);
#pragma unroll
            for (int i = 0; i < 8; ++i) acc[i] = bf2f((ushort)v[i]) * dd;
        }

        int k = rowptr[d], end = rowptr[d + 1];
        while (k + 4 <= end) {
            int s0 = csr[k], s1 = csr[k + 1], s2 = csr[k + 2], s3 = csr[k + 3];
            float w0 = dinv[s0], w1 = dinv[s1], w2 = dinv[s2], w3 = dinv[s3];
            short8 v0 = *(const short8*)(colbase + (size_t)s0 * CC);
            short8 v1 = *(const short8*)(colbase + (size_t)s1 * CC);
            short8 v2 = *(const short8*)(colbase + (size_t)s2 * CC);
            short8 v3 = *(const short8*)(colbase + (size_t)s3 * CC);
#pragma unroll
            for (int i = 0; i < 8; ++i)
                acc[i] += (fmaf(bf2f((ushort)v0[i]), w0, bf2f((ushort)v1[i]) * w1)) +
                          (fmaf(bf2f((ushort)v2[i]), w2, bf2f((ushort)v3[i]) * w3));
            k += 4;
        }
        if (k + 2 <= end) {
            int s0 = csr[k], s1 = csr[k + 1];
            float w0 = dinv[s0], w1 = dinv[s1];
            short8 v0 = *(const short8*)(colbase + (size_t)s0 * CC);
            short8 v1 = *(const short8*)(colbase + (size_t)s1 * CC);
#pragma unroll
            for (int i = 0; i < 8; ++i)
                acc[i] += fmaf(bf2f((ushort)v0[i]), w0, bf2f((ushort)v1[i]) * w1);
            k += 2;
        }
        if (k < end) {
            int s0 = csr[k];
            float w0 = dinv[s0];
            short8 v0 = *(const short8*)(colbase + (size_t)s0 * CC);
#pragma unroll
            for (int i = 0; i < 8; ++i) acc[i] = fmaf(bf2f((ushort)v0[i]), w0, acc[i]);
        }

        float o[8];
#pragma unroll
        for (int i = 0; i < 8; ++i) o[i] = fmaf(acc[i], dd, bb[i]);

        if constexpr (STATS) {
#pragma unroll
            for (int i = 0; i < 8; ++i) { s[i] += o[i]; q[i] = fmaf(o[i], o[i], q[i]); }
        }

        if constexpr (OUT_BF16) {
            short8 v;
#pragma unroll
            for (int i = 0; i < 8; ++i) v[i] = (short)f2bf(o[i]);
            *(short8*)((ushort*)OUT + (size_t)d * CC + j * 8) = v;
        } else {
            float* op = (float*)OUT + (size_t)d * CC + j * 8;
#pragma unroll
            for (int i = 0; i < 8; ++i) op[i] = o[i];
        }
    }

    if constexpr (STATS) {
        __shared__ float reds[16 * 16 * 9];
        __shared__ float redq[16 * 16 * 9];
        float* ps = reds + (slot * 16 + j) * 9;
        float* pq = redq + (slot * 16 + j) * 9;
#pragma unroll
        for (int i = 0; i < 8; ++i) { ps[i] = s[i]; pq[i] = q[i]; }
        __syncthreads();
        for (int off = 8; off > 0; off >>= 1) {
            if (slot < off) {
                float* os = reds + ((slot + off) * 16 + j) * 9;
                float* oq = redq + ((slot + off) * 16 + j) * 9;
#pragma unroll
                for (int i = 0; i < 8; ++i) { ps[i] += os[i]; pq[i] += oq[i]; }
            }
            __syncthreads();
        }
        if (slot == 0) {
#pragma unroll
            for (int i = 0; i < 8; ++i) {
                partT[(size_t)(j * 8 + i) * NB1 + blockIdx.x] = ps[i];
                partT[(size_t)(CC + j * 8 + i) * NB1 + blockIdx.x] = pq[i];
            }
        }
    }
}

// ---------------- BN finish: reduce partials + compute coef (one launch) -----
__global__ __launch_bounds__(256) void bn_finish(const float* __restrict__ partT,
                                                 const float* __restrict__ gamma,
                                                 const float* __restrict__ beta,
                                                 float* __restrict__ coef, int n) {
    __shared__ float red[256];
    int c = blockIdx.x;
    int t = threadIdx.x;

    f32x4 v = ((const f32x4*)(partT + (size_t)c * NB1))[t];
    red[t] = v.x + v.y + v.z + v.w;
    __syncthreads();
    for (int off = 128; off > 0; off >>= 1) {
        if (t < off) red[t] += red[t + off];
        __syncthreads();
    }
    float S = red[0];
    __syncthreads();

    v = ((const f32x4*)(partT + (size_t)(CC + c) * NB1))[t];
    red[t] = v.x + v.y + v.z + v.w;
    __syncthreads();
    for (int off = 128; off > 0; off >>= 1) {
        if (t < off) red[t] += red[t + off];
        __syncthreads();
    }
    float Q = red[0];

    if (t == 0) {
        float inv_n = 1.0f / (float)n;
        float mean = S * inv_n;
        float var = Q * inv_n - mean * mean;
        float sc = gamma[c] * rsqrtf(var + 1e-5f);
        coef[c] = sc;
        coef[CC + c] = beta[c] - mean * sc;
    }
}

extern "C" void kernel_launch(void* const* d_in, const int* in_sizes, int n_in,
                              void* d_out, int out_size, void* d_ws, size_t ws_size,
                              hipStream_t stream) {
    const float* x      = (const float*)d_in[0];
    const float* W1     = (const float*)d_in[1];
    const float* b1     = (const float*)d_in[2];
    const float* gamma1 = (const float*)d_in[3];
    const float* beta1  = (const float*)d_in[4];
    const float* W2     = (const float*)d_in[5];
    const float* b2     = (const float*)d_in[6];
    const int*   edge   = (const int*)d_in[7];

    int n = in_sizes[0] / CC;
    int e = in_sizes[7] / 2;
    const int* src = edge;
    const int* dst = edge + e;

    float* out = (float*)d_out;
    char* ws = (char*)d_ws;
    ushort* hs   = (ushort*)ws;  ws += (size_t)n * CC * 2;   // gemm out (bf16)
    ushort* A    = (ushort*)ws;  ws += (size_t)n * CC * 2;   // agg1 out (bf16)
    ushort* Wt1  = (ushort*)ws;  ws += CC * CC * 2;
    ushort* Wt2  = (ushort*)ws;  ws += CC * CC * 2;
    int*   deg    = (int*)ws;    ws += (size_t)((n + 3) & ~3) * 4;
    float* dinv   = (float*)ws;  ws += (size_t)n * 4;
    int*   rowptr = (int*)ws;    ws += (size_t)(n + 1) * 4;
    int*   rank   = (int*)ws;    ws += (size_t)e * 4;
    int*   csr    = (int*)ws;    ws += (size_t)e * 4;
    int*   tsum   = (int*)ws;    ws += 4096;
    float* coef   = (float*)ws;  ws += 2 * CC * 4;
    float* partT  = (float*)ws;  ws += (size_t)2 * CC * NB1 * 4;   // 1 MB

    int ntiles = (n + TILE - 1) / TILE;
    int gemm_grid = (n + 63) / 64;
    int agg_grid = (n + 15) / 16;
    int n4 = (n + 3) / 4;
    int nzb = (n4 + 255) / 256;
    int edge_blocks = (e + 255) / 256;

    // ---- prep: zero deg + convert W1,W2 ----
    prep<<<nzb + 128, 256, 0, stream>>>((int4*)deg, n4, nzb, W1, Wt1, W2, Wt2);

    // ---- mega: layer-1 GEMM (no graph dep) || count_deg + rank capture ----
    gemm_mfma<float, false, true><<<gemm_grid + edge_blocks, 256, 0, stream>>>(
        x, Wt1, hs, n, nullptr, dst, deg, rank, e, gemm_grid);

    // ---- graph structure: scan (+dinv) + ATOMIC-FREE fill ----
    scan_tile_sums<<<ntiles, 256, 0, stream>>>(deg, tsum, n);
    scan_final<<<ntiles, 256, 0, stream>>>(deg, tsum, ntiles, rowptr, dinv, n);
    fill_csr<<<edge_blocks, 256, 0, stream>>>(src, dst, rowptr, rank, csr, e);

    // ---- layer 1 aggregation + fused BN stats (grid-stride, NB1 blocks) ----
    aggregate_csr<true, true><<<NB1, 256, 0, stream>>>(hs, rowptr, csr, dinv, b1,
                                                       A, partT, n);

    // ---- BN finish: reduce partials + coefficients ----
    bn_finish<<<CC, 256, 0, stream>>>(partT, gamma1, beta1, coef, n);

    // ---- layer 2 (BN+ReLU fused into A-fragment load) ----
    gemm_mfma<ushort, true, false><<<gemm_grid, 256, 0, stream>>>(
        A, Wt2, hs, n, coef, nullptr, nullptr, nullptr, 0, gemm_grid);
    aggregate_csr<false, false><<<agg_grid, 256, 0, stream>>>(hs, rowptr, csr, dinv, b2,
                                                              out, nullptr, n);
}